// Round 3
// baseline (199.536 us; speedup 1.0000x reference)
//
#include <hip/hip_runtime.h>
#include <hip/hip_bf16.h>

// Shapes: B=4, LQ=LKV=1024, D=1024, H=16, HD=64, N=H*HD=1024, M=B*LQ=4096
// ws (u16, 56 MB): Aq 4M | Ac 4M | Wqt 1M | Wkt 1M | Wvt 1M | Wot 1M |
//                  qws 4M (x0.125) | kws 4M | vtws 4M (dim-major) | mws 4M

typedef unsigned short u16;
typedef __attribute__((ext_vector_type(8))) short short8;   // 8 bf16 = 4 VGPRs
typedef __attribute__((ext_vector_type(4))) float f32x4;

__device__ __forceinline__ float bf2f(u16 u) {
    union { unsigned int i; float f; } c;
    c.i = ((unsigned int)u) << 16;
    return c.f;
}

__device__ __forceinline__ u16 f2bf(float f) {
    unsigned int x = __float_as_uint(f);
    unsigned int r = (x + 0x7fffu + ((x >> 16) & 1u)) >> 16;  // RNE
    return (u16)r;
}

// async global->LDS, 16B/lane; lds base MUST be wave-uniform (HW adds lane*16)
__device__ __forceinline__ void glds16(u16* lds, const u16* g) {
    __builtin_amdgcn_global_load_lds(
        (const __attribute__((address_space(1))) void*)g,
        (__attribute__((address_space(3))) void*)lds, 16, 0, 0);
}

// raw-barrier discipline (no __syncthreads in pipelined loops: it drains vmcnt)
#define FENCE() asm volatile("" ::: "memory")
#define BAR() do { FENCE(); __builtin_amdgcn_s_barrier(); FENCE(); } while (0)
// rule 18: sched_barrier(0) after inline-asm waitcnt so MFMA can't hoist past it
#define WAIT_LGKM0() do { asm volatile("s_waitcnt lgkmcnt(0)" ::: "memory"); \
                          __builtin_amdgcn_sched_barrier(0); } while (0)
#define WAIT_VM6() do { asm volatile("s_waitcnt vmcnt(6)" ::: "memory"); \
                        __builtin_amdgcn_sched_barrier(0); } while (0)
#define WAIT_VM4() do { asm volatile("s_waitcnt vmcnt(4)" ::: "memory"); \
                        __builtin_amdgcn_sched_barrier(0); } while (0)
#define WAIT_VM0() do { asm volatile("s_waitcnt vmcnt(0)" ::: "memory"); \
                        __builtin_amdgcn_sched_barrier(0); } while (0)

// ---------------------------------------------------------------------------
// Fused pre-pass, flat grid 5120 blocks x 256 thr (unchanged)
// ---------------------------------------------------------------------------
__global__ __launch_bounds__(256) void prep(
    const float* __restrict__ q, const float* __restrict__ ctx,
    const float* __restrict__ Wq, const float* __restrict__ Wk,
    const float* __restrict__ Wv, const float* __restrict__ Wo,
    u16* __restrict__ Aq, u16* __restrict__ Ac,
    u16* __restrict__ Wqt, u16* __restrict__ Wkt,
    u16* __restrict__ Wvt, u16* __restrict__ Wot)
{
    __shared__ float ls[64][65];
    const int t = threadIdx.x;
    int bid = blockIdx.x;

    if (bid < 4096) {
        const float* in = (bid < 2048) ? q : ctx;
        u16* out = (bid < 2048) ? Aq : Ac;
        size_t i = ((size_t)(bid & 2047) * 256 + t) * 8;
        float4 v0 = *(const float4*)(in + i);
        float4 v1 = *(const float4*)(in + i + 4);
        short8 p;
        p[0] = (short)f2bf(v0.x); p[1] = (short)f2bf(v0.y);
        p[2] = (short)f2bf(v0.z); p[3] = (short)f2bf(v0.w);
        p[4] = (short)f2bf(v1.x); p[5] = (short)f2bf(v1.y);
        p[6] = (short)f2bf(v1.z); p[7] = (short)f2bf(v1.w);
        *(short8*)(out + i) = p;
        return;
    }
    bid -= 4096;
    const float* in; u16* out; int C; size_t moff; int rt, ct;
    if (bid < 768) {
        const int m = bid >> 8, idx = bid & 255;
        in = (m == 0) ? Wq : (m == 1) ? Wk : Wv;
        out = (m == 0) ? Wqt : (m == 1) ? Wkt : Wvt;
        C = 64; rt = (idx & 15) * 64; ct = 0; moff = (size_t)(idx >> 4) * 65536;
    } else {
        const int idx = bid - 768;
        in = Wo; out = Wot; C = 1024; moff = 0;
        rt = (idx & 15) * 64; ct = (idx >> 4) * 64;
    }
    #pragma unroll
    for (int i = 0; i < 4; ++i) {
        int s = i * 256 + t;
        int row = s >> 4, chunk = s & 15;
        float4 v = *(const float4*)(in + moff + (size_t)(rt + row) * C + ct + chunk * 4);
        ls[row][chunk * 4 + 0] = v.x;
        ls[row][chunk * 4 + 1] = v.y;
        ls[row][chunk * 4 + 2] = v.z;
        ls[row][chunk * 4 + 3] = v.w;
    }
    __syncthreads();
    #pragma unroll
    for (int i = 0; i < 2; ++i) {
        int s = i * 256 + t;
        int n = s >> 3, kc = s & 7;
        short8 p;
        #pragma unroll
        for (int j = 0; j < 8; ++j) p[j] = (short)f2bf(ls[kc * 8 + j][n]);
        *(short8*)(out + moff + (size_t)(ct + n) * 1024 + rt + kc * 8) = p;
    }
}

// ---------------------------------------------------------------------------
// Q/K/V projection v4: 256x256 tile, BK=64, 8-phase schedule (T3+T4+T5),
// counted vmcnt(4) (never 0 mid-loop), raw s_barrier, setprio around MFMA.
// grid = 192 blocks x 512 thr (8 waves, 2Mx4N; per-wave 128x64 output).
// (unchanged this round)
// ---------------------------------------------------------------------------
__global__ __launch_bounds__(512) void gemm_qkv8(
    const u16* __restrict__ Aq, const u16* __restrict__ Ac,
    const u16* __restrict__ Wqt, const u16* __restrict__ Wkt,
    const u16* __restrict__ Wvt,
    const float* __restrict__ bq, const float* __restrict__ bk,
    const float* __restrict__ bv,
    u16* __restrict__ qws, u16* __restrict__ kws, u16* __restrict__ vtws)
{
    __shared__ u16 lds[2][2][256 * 64];   // [parity][0=A,1=B][row][k]  128 KB

    const int tid = threadIdx.x;
    const int w = tid >> 6, lane = tid & 63;
    const int wr = w >> 2, wc = w & 3;                 // 2 x 4 wave grid
    const int quad = lane >> 4, c = lane & 15, cx = c & 7;
    const int sr = tid >> 3;                           // staging row (0..63)
    const int gch = (tid & 7) ^ (sr & 7);              // source-side swizzle

    // 192 blocks: xcd owns 2 mtiles x 4 nt x 3 z (24 blocks, all co-resident)
    const int f = blockIdx.x;
    const int xcd = f & 7, r = f >> 3;                 // r 0..23
    const int z = r >> 3;                              // 0..2
    const int mt = xcd * 2 + ((r >> 2) & 1);           // 0..15
    const int nt = r & 3;                              // 0..3
    const int m0 = mt * 256, n0 = nt * 256;

    const u16* A = (z == 0) ? Aq : Ac;
    const u16* Wt = (z == 0) ? Wqt : (z == 1) ? Wkt : Wvt;
    const float* bias = (z == 0) ? bq : (z == 1) ? bk : bv;

    const u16* gAt = A + (size_t)(m0 + sr) * 1024 + gch * 8;
    const u16* gBt = Wt + (size_t)(n0 + sr) * 1024 + gch * 8;

    auto stageA = [&](int par, int half, int t) {      // one 128x64 half-tile
        const u16* g = gAt + (size_t)half * 128 * 1024 + t * 64;
        u16* l = &lds[par][0][(half * 128 + w * 8) * 64];
        glds16(l, g);
        glds16(l + 64 * 64, g + (size_t)64 * 1024);
    };
    auto stageB = [&](int par, int half, int t) {
        const u16* g = gBt + (size_t)half * 128 * 1024 + t * 64;
        u16* l = &lds[par][1][(half * 128 + w * 8) * 64];
        glds16(l, g);
        glds16(l + 64 * 64, g + (size_t)64 * 1024);
    };

    f32x4 acc[8][4] = {};          // [mh*4+mf][nh*2+nf]
    short8 aq[4][2], bA[2][2], bB[2][2];

    auto ldA = [&](int par, int mh) {
        #pragma unroll
        for (int mf = 0; mf < 4; ++mf)
            #pragma unroll
            for (int ks = 0; ks < 2; ++ks)
                aq[mf][ks] = *(const short8*)&lds[par][0][
                    (wr * 128 + mh * 64 + mf * 16 + c) * 64 + (((ks * 4 + quad) ^ cx) * 8)];
    };
    auto ldB = [&](int par, int nh, short8 (&bq_)[2][2]) {
        #pragma unroll
        for (int nf = 0; nf < 2; ++nf)
            #pragma unroll
            for (int ks = 0; ks < 2; ++ks)
                bq_[nf][ks] = *(const short8*)&lds[par][1][
                    (wc * 64 + nh * 32 + nf * 16 + c) * 64 + (((ks * 4 + quad) ^ cx) * 8)];
    };
    auto mma = [&](int mh, int nh, short8 (&bq_)[2][2]) {
        #pragma unroll
        for (int mf = 0; mf < 4; ++mf)
            #pragma unroll
            for (int nf = 0; nf < 2; ++nf)
                #pragma unroll
                for (int ks = 0; ks < 2; ++ks)
                    acc[mh * 4 + mf][nh * 2 + nf] =
                        __builtin_amdgcn_mfma_f32_16x16x32_bf16(
                            aq[mf][ks], bq_[nf][ks], acc[mh * 4 + mf][nh * 2 + nf], 0, 0, 0);
    };

    // prologue: tile0 full + tile1 B halves (A halves of tile1 arrive in ph1/ph2).
    // vmcnt(4) leaves exactly the 2 tile-1 B issues outstanding -> tile0 landed.
    stageB(0, 0, 0); stageB(0, 1, 0); stageA(0, 0, 0); stageA(0, 1, 0);
    stageB(1, 0, 1); stageB(1, 1, 1);
    WAIT_VM4(); BAR();

    #pragma unroll 1
    for (int i = 0; i < 8; ++i) {
        const int o = 2 * i + 1, e = 2 * i + 2;   // odd tile of this iter, next even

        // ph1: even tile (m0,n0); prefetch A0(odd)  [buf1.A free since prev ph7]
        ldA(0, 0); ldB(0, 0, bA);
        stageA(1, 0, o);
        BAR(); WAIT_LGKM0();
        __builtin_amdgcn_s_setprio(1); mma(0, 0, bA); __builtin_amdgcn_s_setprio(0);
        BAR();
        // ph2: (m0,n1); prefetch A1(odd)
        ldB(0, 1, bB);
        stageA(1, 1, o);
        BAR(); WAIT_LGKM0();
        __builtin_amdgcn_s_setprio(1); mma(0, 1, bB); __builtin_amdgcn_s_setprio(0);
        BAR();
        // ph3: (m1,n1); prefetch B0(even')  [buf0.B free after ph2]
        ldA(0, 1);
        if (i < 7) stageB(0, 0, e);
        BAR(); WAIT_LGKM0();
        __builtin_amdgcn_s_setprio(1); mma(1, 1, bB); __builtin_amdgcn_s_setprio(0);
        BAR();
        // ph4: (m1,n0) on regs from ph1; prefetch B1(even'); vm-wait for odd tile
        if (i < 7) stageB(0, 1, e);
        BAR();
        __builtin_amdgcn_s_setprio(1); mma(1, 0, bA); __builtin_amdgcn_s_setprio(0);
        if (i < 7) { WAIT_VM4(); } else { WAIT_VM0(); }   // last iter: drain
        BAR();
        // ph5: odd tile (m0,n0); prefetch A0(even')  [buf0.A free after ph3]
        ldA(1, 0); ldB(1, 0, bA);
        if (i < 7) stageA(0, 0, e);
        BAR(); WAIT_LGKM0();
        __builtin_amdgcn_s_setprio(1); mma(0, 0, bA); __builtin_amdgcn_s_setprio(0);
        BAR();
        // ph6: (m0,n1); prefetch A1(even')
        ldB(1, 1, bB);
        if (i < 7) stageA(0, 1, e);
        BAR(); WAIT_LGKM0();
        __builtin_amdgcn_s_setprio(1); mma(0, 1, bB); __builtin_amdgcn_s_setprio(0);
        BAR();
        // ph7: (m1,n1); prefetch B0(odd')  [buf1.B free after ph6]
        ldA(1, 1);
        if (i < 7) stageB(1, 0, e + 1);
        BAR(); WAIT_LGKM0();
        __builtin_amdgcn_s_setprio(1); mma(1, 1, bB); __builtin_amdgcn_s_setprio(0);
        BAR();
        // ph8: (m1,n0); prefetch B1(odd'); vm-wait for even tile
        if (i < 7) stageB(1, 1, e + 1);
        BAR();
        __builtin_amdgcn_s_setprio(1); mma(1, 0, bA); __builtin_amdgcn_s_setprio(0);
        if (i < 7) WAIT_VM4();
        BAR();
    }

    // ---- epilogue ----
    const int h = nt * 4 + wc;                 // wave wc owns one head
    const int b = m0 >> 10;                    // 256-row tile never crosses batch
    const int lbase = (m0 & 1023) + wr * 128;

    float bb[4];
    #pragma unroll
    for (int cn = 0; cn < 4; ++cn)
        bb[cn] = bias[h * 64 + (cn >> 1) * 32 + (cn & 1) * 16 + c];

    if (z < 2) {
        u16* dst = (z == 0) ? qws : kws;
        const float scale = (z == 0) ? 0.125f : 1.0f;
        u16* dbase = dst + (size_t)(b * 16 + h) * 1024 * 64;
        #pragma unroll
        for (int mi = 0; mi < 8; ++mi) {
            const int ro = (mi >> 2) * 64 + (mi & 3) * 16;
            const int rowb = lbase + ro + quad * 4;
            #pragma unroll
            for (int rr = 0; rr < 4; ++rr) {
                u16* drow = dbase + (size_t)(rowb + rr) * 64;
                #pragma unroll
                for (int cn = 0; cn < 4; ++cn) {
                    const int hd = (cn >> 1) * 32 + (cn & 1) * 16 + c;
                    drow[hd] = f2bf((acc[mi][cn][rr] + bb[cn]) * scale);
                }
            }
        }
    } else {
        // V: vtws [B,H,64,1024] dim-major; 4 acc regs = 4 consecutive l -> ushort4
        u16* dbase = vtws + (size_t)(b * 16 + h) * 64 * 1024;
        #pragma unroll
        for (int mi = 0; mi < 8; ++mi) {
            const int ro = (mi >> 2) * 64 + (mi & 3) * 16;
            const int l0 = lbase + ro + quad * 4;
            #pragma unroll
            for (int cn = 0; cn < 4; ++cn) {
                const int hd = (cn >> 1) * 32 + (cn & 1) * 16 + c;
                ushort4 pk;
                pk.x = f2bf(acc[mi][cn][0] + bb[cn]);
                pk.y = f2bf(acc[mi][cn][1] + bb[cn]);
                pk.z = f2bf(acc[mi][cn][2] + bb[cn]);
                pk.w = f2bf(acc[mi][cn][3] + bb[cn]);
                *(ushort4*)(dbase + (size_t)hd * 1024 + l0) = pk;
            }
        }
    }
}

// ---------------------------------------------------------------------------
// Output projection v4: 2-phase counted pipeline (unchanged this round)
// ---------------------------------------------------------------------------
__global__ __launch_bounds__(256) void gemm_out(
    const u16* __restrict__ A, const u16* __restrict__ Wot,
    const float* __restrict__ bo, float* __restrict__ out)
{
    __shared__ u16 As[2][128 * 64];   // 32 KB
    __shared__ u16 Bs[2][64 * 64];    // 16 KB
    const int f = blockIdx.x;
    const int xcd = f & 7, k = f >> 3;
    const int m0 = (xcd * 4 + (k & 3)) * 128;
    const int n0 = (k >> 2) * 64;
    const int t = threadIdx.x;
    const int w = t >> 6, lane = t & 63;
    const int quad = lane >> 4, c = lane & 15;
    const int cx = c & 7;

    const int sr = w * 8 + (lane >> 3);
    const int gch = (lane & 7) ^ ((lane >> 3) & 7);
    const u16* gA = A + (size_t)(m0 + sr) * 1024 + gch * 8;
    const u16* gB = Wot + (size_t)(n0 + sr) * 1024 + gch * 8;

    const int arow = (w >> 1) * 64 + c;
    const int brow = (w & 1) * 32 + c;

    auto stage = [&](int par, int kt) {        // 6 glds16 per thread
        #pragma unroll
        for (int i = 0; i < 4; ++i)
            glds16(As[par] + (i * 32 + w * 8) * 64, gA + (size_t)i * 32 * 1024 + kt);
        #pragma unroll
        for (int i = 0; i < 2; ++i)
            glds16(Bs[par] + (i * 32 + w * 8) * 64, gB + (size_t)i * 32 * 1024 + kt);
    };

    f32x4 acc[4][2] = {};
    stage(0, 0);
    stage(1, 64);
    // outstanding: 12. steady state: wait(6) -> tile i landed, tile i+1 in flight.
    #pragma unroll 1
    for (int i = 0; i < 16; ++i) {
        const int cur = i & 1;
        if (i < 15) { WAIT_VM6(); } else { WAIT_VM0(); }
        BAR();
        #pragma unroll
        for (int kh = 0; kh < 2; ++kh) {
            const int ch = (kh * 4 + quad);
            short8 af[4], bf[2];
            #pragma unroll
            for (int rs = 0; rs < 4; ++rs)
                af[rs] = *(const short8*)(As[cur] + (arow + rs * 16) * 64 + (ch ^ cx) * 8);
            #pragma unroll
            for (int cs = 0; cs < 2; ++cs)
                bf[cs] = *(const short8*)(Bs[cur] + (brow + cs * 16) * 64 + (ch ^ cx) * 8);
            #pragma unroll
            for (int rs = 0; rs < 4; ++rs)
                #pragma unroll
                for (int cs = 0; cs < 2; ++cs)
                    acc[rs][cs] = __builtin_amdgcn_mfma_f32_16x16x32_bf16(
                        af[rs], bf[cs], acc[rs][cs], 0, 0, 0);
        }
        BAR();                       // all waves done reading buf cur
        if (i < 14) stage(cur, (i + 2) * 64);
    }

    const int nb = n0 + (w & 1) * 32;
    float bb[2];
    #pragma unroll
    for (int cs = 0; cs < 2; ++cs) bb[cs] = bo[nb + cs * 16 + c];

    #pragma unroll
    for (int rs = 0; rs < 4; ++rs) {
        #pragma unroll
        for (int r = 0; r < 4; ++r) {
            const int row = m0 + (w >> 1) * 64 + rs * 16 + quad * 4 + r;
            float* orow = out + (size_t)row * 1024 + nb;
            #pragma unroll
            for (int cs = 0; cs < 2; ++cs)
                orow[cs * 16 + c] = acc[rs][cs][r] + bb[cs];
        }
    }
}

// ---------------------------------------------------------------------------
// MFMA flash attention v7: fat waves. Each wave owns 64 q-rows (4 row-blocks);
// K/V fragments read from LDS ONCE per tile per wave and reused across all 4
// row-blocks -> per-q-row LDS traffic / 4 (attn was DS-pipe-throughput-bound:
// 4 waves x 18 b128 x 12cyc x 64 tile-iters ~ 32us of DS issue at v6 shape).
// Grid 256 blocks (1/CU, 32/XCD), 4 waves x 64 rows = 256 q-rows per block.
// Pipeline (dbuf + counted vmcnt(4)), swizzles, P layout: carried over intact.
// ---------------------------------------------------------------------------
__global__ __launch_bounds__(256, 1) void attn_mfma(
    const u16* __restrict__ qws, const u16* __restrict__ kws,
    const u16* __restrict__ vtws, u16* __restrict__ multi,
    float* __restrict__ resid)
{
    __shared__ u16 Ks[2][64 * 64];     // [par][key][dim], chunk-swizzled (16 KB)
    __shared__ u16 Vs[2][64 * 64];     // [par][dim][key], chunk-swizzled (16 KB)
    __shared__ u16 Ps[4][16 * 64];     // per-wave P [16][64], chunk-XOR swizzled (8 KB)
    const int t = threadIdx.x;
    const int wave = t >> 6, lane = t & 63;
    const int quad = lane >> 4, c = lane & 15;
    const int cx = c & 7;
    const int f = blockIdx.x;                  // 256 blocks
    const int xcd = f & 7, j = f >> 3;         // j 0..31
    const int bh = xcd * 8 + (j & 7);          // 8 heads per XCD (KV L2-resident)
    const int qt = j >> 3;                     // 0..3
    const int b = bh >> 4, h = bh & 15;
    const int q0 = qt * 256 + wave * 64;       // 64 q-rows per wave

    const u16* qb = qws + ((size_t)bh * 1024 + q0) * 64;
    const u16* kb = kws + (size_t)bh * 65536;
    const u16* vb = vtws + (size_t)bh * 65536;

    // Q fragments for 4 row-blocks (rows rb*16 + c), k-halves 0/1
    short8 qa[4][2];
    #pragma unroll
    for (int rb = 0; rb < 4; ++rb) {
        qa[rb][0] = *(const short8*)(qb + (size_t)(rb * 16 + c) * 64 + quad * 8);
        qa[rb][1] = *(const short8*)(qb + (size_t)(rb * 16 + c) * 64 + 32 + quad * 8);
    }

    const int srow = wave * 16 + (lane >> 3);
    const int gch = (lane & 7) ^ ((lane >> 3) & 7);
    const u16* gK0 = kb + (size_t)srow * 64 + gch * 8;
    const u16* gK1 = kb + (size_t)(srow + 8) * 64 + gch * 8;
    const u16* gV0 = vb + (size_t)srow * 1024 + gch * 8;
    const u16* gV1 = vb + (size_t)(srow + 8) * 1024 + gch * 8;

    // 4 glds16 per stage -> vmcnt +4; steady-state outstanding = 8 (2 tiles)
    auto stage = [&](int par, int kt) {
        glds16(Ks[par] + (wave * 16) * 64,     gK0 + (size_t)kt * 64);
        glds16(Ks[par] + (wave * 16 + 8) * 64, gK1 + (size_t)kt * 64);
        glds16(Vs[par] + (wave * 16) * 64,     gV0 + kt);
        glds16(Vs[par] + (wave * 16 + 8) * 64, gV1 + kt);
    };

    f32x4 O[4][4] = {};                // [rb][nt]
    float ps[4][4] = {};               // [rb][r]
    u16* pw = &Ps[wave][0];

    stage(0, 0);
    stage(1, 64);

    #pragma unroll 1
    for (int i = 0; i < 16; ++i) {
        const int cur = i & 1;
        if (i < 15) { WAIT_VM4(); } else { WAIT_VM0(); }  // tile i landed
        BAR();

        const u16* Kc = Ks[cur];
        const u16* Vc = Vs[cur];

        // hoist K/V fragments once per tile; reused by all 4 row-blocks
        short8 kf[4][2], vf[4][2];
        #pragma unroll
        for (int nt = 0; nt < 4; ++nt) {
            const u16* kr = Kc + (nt * 16 + c) * 64;
            kf[nt][0] = *(const short8*)(kr + ((quad ^ cx)) * 8);
            kf[nt][1] = *(const short8*)(kr + (((4 + quad) ^ cx)) * 8);
            const u16* vr = Vc + (nt * 16 + c) * 64;
            vf[nt][0] = *(const short8*)(vr + ((quad ^ cx)) * 8);
            vf[nt][1] = *(const short8*)(vr + (((4 + quad) ^ cx)) * 8);
        }

        #pragma unroll
        for (int rb = 0; rb < 4; ++rb) {
            f32x4 s[4];
            __builtin_amdgcn_s_setprio(1);
            #pragma unroll
            for (int nt = 0; nt < 4; ++nt) {
                f32x4 z = {};
                z = __builtin_amdgcn_mfma_f32_16x16x32_bf16(qa[rb][0], kf[nt][0], z, 0, 0, 0);
                z = __builtin_amdgcn_mfma_f32_16x16x32_bf16(qa[rb][1], kf[nt][1], z, 0, 0, 0);
                s[nt] = z;
            }
            __builtin_amdgcn_s_setprio(0);

            // P store: row prow = quad*4+r, col = nt*16+c; chunk' = chunk ^ (prow&7)
            #pragma unroll
            for (int nt = 0; nt < 4; ++nt)
                #pragma unroll
                for (int r = 0; r < 4; ++r) {
                    float p = __expf(s[nt][r]);
                    ps[rb][r] += p;
                    const int prow = quad * 4 + r;
                    pw[prow * 64 + (((nt * 2 + (c >> 3)) ^ (prow & 7)) * 8) + (c & 7)]
                        = (u16)(__float_as_uint(p) >> 16);
                }
            short8 pa0 = *(const short8*)(pw + c * 64 + ((quad ^ cx)) * 8);
            short8 pa1 = *(const short8*)(pw + c * 64 + (((4 + quad) ^ cx)) * 8);

            __builtin_amdgcn_s_setprio(1);
            #pragma unroll
            for (int nt = 0; nt < 4; ++nt) {
                O[rb][nt] = __builtin_amdgcn_mfma_f32_16x16x32_bf16(pa0, vf[nt][0], O[rb][nt], 0, 0, 0);
                O[rb][nt] = __builtin_amdgcn_mfma_f32_16x16x32_bf16(pa1, vf[nt][1], O[rb][nt], 0, 0, 0);
            }
            __builtin_amdgcn_s_setprio(0);
        }

        BAR();                         // all waves done reading buf cur
        if (i < 14) stage(cur, (i + 2) * 64);
    }

    #pragma unroll
    for (int rb = 0; rb < 4; ++rb) {
        float inv[4];
        #pragma unroll
        for (int r = 0; r < 4; ++r) {
            float sum = ps[rb][r];
            sum += __shfl_xor(sum, 1);
            sum += __shfl_xor(sum, 2);
            sum += __shfl_xor(sum, 4);
            sum += __shfl_xor(sum, 8);
            inv[r] = 1.0f / sum;
        }
        u16* ob = multi + ((size_t)b * 1024 + q0 + rb * 16 + quad * 4) * 1024 + h * 64 + c;
        #pragma unroll
        for (int r = 0; r < 4; ++r) {
            u16* orow = ob + (size_t)r * 1024;
            orow[0]  = f2bf(O[rb][0][r] * inv[r]);
            orow[16] = f2bf(O[rb][1][r] * inv[r]);
            orow[32] = f2bf(O[rb][2][r] * inv[r]);
            orow[48] = f2bf(O[rb][3][r] * inv[r]);
        }

        // resid epilogue: lane holds Q[q0+rb*16+c][quad*8..] in qa[rb] (scaled 1/8)
        float* rr = resid + ((size_t)b * 1024 + q0 + rb * 16 + c) * 1024 + h * 64;
        #pragma unroll
        for (int jj = 0; jj < 8; ++jj) {
            rr[quad * 8 + jj]      = bf2f((u16)qa[rb][0][jj]) * 8.0f;
            rr[32 + quad * 8 + jj] = bf2f((u16)qa[rb][1][jj]) * 8.0f;
        }
    }
}

extern "C" void kernel_launch(void* const* d_in, const int* in_sizes, int n_in,
                              void* d_out, int out_size, void* d_ws, size_t ws_size,
                              hipStream_t stream) {
    const float* queries = (const float*)d_in[0];
    const float* context = (const float*)d_in[1];
    const float* Wq = (const float*)d_in[2];
    const float* bq = (const float*)d_in[3];
    const float* Wk = (const float*)d_in[4];
    const float* bk = (const float*)d_in[5];
    const float* Wv = (const float*)d_in[6];
    const float* bv = (const float*)d_in[7];
    const float* Wo = (const float*)d_in[8];
    const float* bo = (const float*)d_in[9];

    float* out = (float*)d_out;                     // [4,1024,1024] f32
    float* resid = out + (size_t)4 * 1024 * 1024;   // [4,1024,1024] f32

    const size_t M1 = 1024 * 1024;
    u16* Aq   = (u16*)d_ws;          // 4M
    u16* Ac   = Aq + 4 * M1;         // 4M
    u16* Wqt  = Ac + 4 * M1;         // 1M
    u16* Wkt  = Wqt + M1;            // 1M
    u16* Wvt  = Wkt + M1;            // 1M
    u16* Wot  = Wvt + M1;            // 1M
    u16* qws  = Wot + M1;            // 4M (pre-scaled 0.125)
    u16* kws  = qws + 4 * M1;        // 4M
    u16* vtws = kws + 4 * M1;        // 4M [B,H,64,1024]
    u16* mws  = vtws + 4 * M1;       // 4M [B,1024,1024]

    prep<<<5120, 256, 0, stream>>>(queries, context, Wq, Wk, Wv, Wo,
                                   Aq, Ac, Wqt, Wkt, Wvt, Wot);
    gemm_qkv8<<<192, 512, 0, stream>>>(Aq, Ac, Wqt, Wkt, Wvt,
                                       bq, bk, bv, qws, kws, vtws);
    attn_mfma<<<256, 256, 0, stream>>>(qws, kws, vtws, mws, resid);
    gemm_out<<<512, 256, 0, stream>>>(mws, Wot, bo, out);
}

// Round 4
// 190.794 us; speedup vs baseline: 1.0458x; 1.0458x over previous
//
#include <hip/hip_runtime.h>
#include <hip/hip_bf16.h>

// Shapes: B=4, LQ=LKV=1024, D=1024, H=16, HD=64, N=H*HD=1024, M=B*LQ=4096
// ws (u16, 56 MB): Aq 4M | Ac 4M | Wqt 1M | Wkt 1M | Wvt 1M | Wot 1M |
//                  qws 4M (x0.125) | kws 4M | vtws 4M (dim-major) | mws 4M

typedef unsigned short u16;
typedef __attribute__((ext_vector_type(8))) short short8;   // 8 bf16 = 4 VGPRs
typedef __attribute__((ext_vector_type(4))) float f32x4;

__device__ __forceinline__ float bf2f(u16 u) {
    union { unsigned int i; float f; } c;
    c.i = ((unsigned int)u) << 16;
    return c.f;
}

__device__ __forceinline__ u16 f2bf(float f) {
    unsigned int x = __float_as_uint(f);
    unsigned int r = (x + 0x7fffu + ((x >> 16) & 1u)) >> 16;  // RNE
    return (u16)r;
}

// async global->LDS, 16B/lane; lds base MUST be wave-uniform (HW adds lane*16)
__device__ __forceinline__ void glds16(u16* lds, const u16* g) {
    __builtin_amdgcn_global_load_lds(
        (const __attribute__((address_space(1))) void*)g,
        (__attribute__((address_space(3))) void*)lds, 16, 0, 0);
}

// raw-barrier discipline (no __syncthreads in pipelined loops: it drains vmcnt)
#define FENCE() asm volatile("" ::: "memory")
#define BAR() do { FENCE(); __builtin_amdgcn_s_barrier(); FENCE(); } while (0)
// rule 18: sched_barrier(0) after inline-asm waitcnt so MFMA can't hoist past it
#define WAIT_LGKM0() do { asm volatile("s_waitcnt lgkmcnt(0)" ::: "memory"); \
                          __builtin_amdgcn_sched_barrier(0); } while (0)
#define WAIT_VM6() do { asm volatile("s_waitcnt vmcnt(6)" ::: "memory"); \
                        __builtin_amdgcn_sched_barrier(0); } while (0)
#define WAIT_VM4() do { asm volatile("s_waitcnt vmcnt(4)" ::: "memory"); \
                        __builtin_amdgcn_sched_barrier(0); } while (0)
#define WAIT_VM0() do { asm volatile("s_waitcnt vmcnt(0)" ::: "memory"); \
                        __builtin_amdgcn_sched_barrier(0); } while (0)

// ---------------------------------------------------------------------------
// Fused pre-pass, flat grid 5120 blocks x 256 thr (unchanged)
// ---------------------------------------------------------------------------
__global__ __launch_bounds__(256) void prep(
    const float* __restrict__ q, const float* __restrict__ ctx,
    const float* __restrict__ Wq, const float* __restrict__ Wk,
    const float* __restrict__ Wv, const float* __restrict__ Wo,
    u16* __restrict__ Aq, u16* __restrict__ Ac,
    u16* __restrict__ Wqt, u16* __restrict__ Wkt,
    u16* __restrict__ Wvt, u16* __restrict__ Wot)
{
    __shared__ float ls[64][65];
    const int t = threadIdx.x;
    int bid = blockIdx.x;

    if (bid < 4096) {
        const float* in = (bid < 2048) ? q : ctx;
        u16* out = (bid < 2048) ? Aq : Ac;
        size_t i = ((size_t)(bid & 2047) * 256 + t) * 8;
        float4 v0 = *(const float4*)(in + i);
        float4 v1 = *(const float4*)(in + i + 4);
        short8 p;
        p[0] = (short)f2bf(v0.x); p[1] = (short)f2bf(v0.y);
        p[2] = (short)f2bf(v0.z); p[3] = (short)f2bf(v0.w);
        p[4] = (short)f2bf(v1.x); p[5] = (short)f2bf(v1.y);
        p[6] = (short)f2bf(v1.z); p[7] = (short)f2bf(v1.w);
        *(short8*)(out + i) = p;
        return;
    }
    bid -= 4096;
    const float* in; u16* out; int C; size_t moff; int rt, ct;
    if (bid < 768) {
        const int m = bid >> 8, idx = bid & 255;
        in = (m == 0) ? Wq : (m == 1) ? Wk : Wv;
        out = (m == 0) ? Wqt : (m == 1) ? Wkt : Wvt;
        C = 64; rt = (idx & 15) * 64; ct = 0; moff = (size_t)(idx >> 4) * 65536;
    } else {
        const int idx = bid - 768;
        in = Wo; out = Wot; C = 1024; moff = 0;
        rt = (idx & 15) * 64; ct = (idx >> 4) * 64;
    }
    #pragma unroll
    for (int i = 0; i < 4; ++i) {
        int s = i * 256 + t;
        int row = s >> 4, chunk = s & 15;
        float4 v = *(const float4*)(in + moff + (size_t)(rt + row) * C + ct + chunk * 4);
        ls[row][chunk * 4 + 0] = v.x;
        ls[row][chunk * 4 + 1] = v.y;
        ls[row][chunk * 4 + 2] = v.z;
        ls[row][chunk * 4 + 3] = v.w;
    }
    __syncthreads();
    #pragma unroll
    for (int i = 0; i < 2; ++i) {
        int s = i * 256 + t;
        int n = s >> 3, kc = s & 7;
        short8 p;
        #pragma unroll
        for (int j = 0; j < 8; ++j) p[j] = (short)f2bf(ls[kc * 8 + j][n]);
        *(short8*)(out + moff + (size_t)(ct + n) * 1024 + rt + kc * 8) = p;
    }
}

// ---------------------------------------------------------------------------
// Q/K/V projection v4: 256x256 tile, BK=64, 8-phase schedule (T3+T4+T5),
// counted vmcnt(4) (never 0 mid-loop), raw s_barrier, setprio around MFMA.
// grid = 192 blocks x 512 thr (8 waves, 2Mx4N; per-wave 128x64 output).
// (unchanged this round)
// ---------------------------------------------------------------------------
__global__ __launch_bounds__(512) void gemm_qkv8(
    const u16* __restrict__ Aq, const u16* __restrict__ Ac,
    const u16* __restrict__ Wqt, const u16* __restrict__ Wkt,
    const u16* __restrict__ Wvt,
    const float* __restrict__ bq, const float* __restrict__ bk,
    const float* __restrict__ bv,
    u16* __restrict__ qws, u16* __restrict__ kws, u16* __restrict__ vtws)
{
    __shared__ u16 lds[2][2][256 * 64];   // [parity][0=A,1=B][row][k]  128 KB

    const int tid = threadIdx.x;
    const int w = tid >> 6, lane = tid & 63;
    const int wr = w >> 2, wc = w & 3;                 // 2 x 4 wave grid
    const int quad = lane >> 4, c = lane & 15, cx = c & 7;
    const int sr = tid >> 3;                           // staging row (0..63)
    const int gch = (tid & 7) ^ (sr & 7);              // source-side swizzle

    // 192 blocks: xcd owns 2 mtiles x 4 nt x 3 z (24 blocks, all co-resident)
    const int f = blockIdx.x;
    const int xcd = f & 7, r = f >> 3;                 // r 0..23
    const int z = r >> 3;                              // 0..2
    const int mt = xcd * 2 + ((r >> 2) & 1);           // 0..15
    const int nt = r & 3;                              // 0..3
    const int m0 = mt * 256, n0 = nt * 256;

    const u16* A = (z == 0) ? Aq : Ac;
    const u16* Wt = (z == 0) ? Wqt : (z == 1) ? Wkt : Wvt;
    const float* bias = (z == 0) ? bq : (z == 1) ? bk : bv;

    const u16* gAt = A + (size_t)(m0 + sr) * 1024 + gch * 8;
    const u16* gBt = Wt + (size_t)(n0 + sr) * 1024 + gch * 8;

    auto stageA = [&](int par, int half, int t) {      // one 128x64 half-tile
        const u16* g = gAt + (size_t)half * 128 * 1024 + t * 64;
        u16* l = &lds[par][0][(half * 128 + w * 8) * 64];
        glds16(l, g);
        glds16(l + 64 * 64, g + (size_t)64 * 1024);
    };
    auto stageB = [&](int par, int half, int t) {
        const u16* g = gBt + (size_t)half * 128 * 1024 + t * 64;
        u16* l = &lds[par][1][(half * 128 + w * 8) * 64];
        glds16(l, g);
        glds16(l + 64 * 64, g + (size_t)64 * 1024);
    };

    f32x4 acc[8][4] = {};          // [mh*4+mf][nh*2+nf]
    short8 aq[4][2], bA[2][2], bB[2][2];

    auto ldA = [&](int par, int mh) {
        #pragma unroll
        for (int mf = 0; mf < 4; ++mf)
            #pragma unroll
            for (int ks = 0; ks < 2; ++ks)
                aq[mf][ks] = *(const short8*)&lds[par][0][
                    (wr * 128 + mh * 64 + mf * 16 + c) * 64 + (((ks * 4 + quad) ^ cx) * 8)];
    };
    auto ldB = [&](int par, int nh, short8 (&bq_)[2][2]) {
        #pragma unroll
        for (int nf = 0; nf < 2; ++nf)
            #pragma unroll
            for (int ks = 0; ks < 2; ++ks)
                bq_[nf][ks] = *(const short8*)&lds[par][1][
                    (wc * 64 + nh * 32 + nf * 16 + c) * 64 + (((ks * 4 + quad) ^ cx) * 8)];
    };
    auto mma = [&](int mh, int nh, short8 (&bq_)[2][2]) {
        #pragma unroll
        for (int mf = 0; mf < 4; ++mf)
            #pragma unroll
            for (int nf = 0; nf < 2; ++nf)
                #pragma unroll
                for (int ks = 0; ks < 2; ++ks)
                    acc[mh * 4 + mf][nh * 2 + nf] =
                        __builtin_amdgcn_mfma_f32_16x16x32_bf16(
                            aq[mf][ks], bq_[nf][ks], acc[mh * 4 + mf][nh * 2 + nf], 0, 0, 0);
    };

    // prologue: tile0 full + tile1 B halves (A halves of tile1 arrive in ph1/ph2).
    // vmcnt(4) leaves exactly the 2 tile-1 B issues outstanding -> tile0 landed.
    stageB(0, 0, 0); stageB(0, 1, 0); stageA(0, 0, 0); stageA(0, 1, 0);
    stageB(1, 0, 1); stageB(1, 1, 1);
    WAIT_VM4(); BAR();

    #pragma unroll 1
    for (int i = 0; i < 8; ++i) {
        const int o = 2 * i + 1, e = 2 * i + 2;   // odd tile of this iter, next even

        // ph1: even tile (m0,n0); prefetch A0(odd)  [buf1.A free since prev ph7]
        ldA(0, 0); ldB(0, 0, bA);
        stageA(1, 0, o);
        BAR(); WAIT_LGKM0();
        __builtin_amdgcn_s_setprio(1); mma(0, 0, bA); __builtin_amdgcn_s_setprio(0);
        BAR();
        // ph2: (m0,n1); prefetch A1(odd)
        ldB(0, 1, bB);
        stageA(1, 1, o);
        BAR(); WAIT_LGKM0();
        __builtin_amdgcn_s_setprio(1); mma(0, 1, bB); __builtin_amdgcn_s_setprio(0);
        BAR();
        // ph3: (m1,n1); prefetch B0(even')  [buf0.B free after ph2]
        ldA(0, 1);
        if (i < 7) stageB(0, 0, e);
        BAR(); WAIT_LGKM0();
        __builtin_amdgcn_s_setprio(1); mma(1, 1, bB); __builtin_amdgcn_s_setprio(0);
        BAR();
        // ph4: (m1,n0) on regs from ph1; prefetch B1(even'); vm-wait for odd tile
        if (i < 7) stageB(0, 1, e);
        BAR();
        __builtin_amdgcn_s_setprio(1); mma(1, 0, bA); __builtin_amdgcn_s_setprio(0);
        if (i < 7) { WAIT_VM4(); } else { WAIT_VM0(); }   // last iter: drain
        BAR();
        // ph5: odd tile (m0,n0); prefetch A0(even')  [buf0.A free after ph3]
        ldA(1, 0); ldB(1, 0, bA);
        if (i < 7) stageA(0, 0, e);
        BAR(); WAIT_LGKM0();
        __builtin_amdgcn_s_setprio(1); mma(0, 0, bA); __builtin_amdgcn_s_setprio(0);
        BAR();
        // ph6: (m0,n1); prefetch A1(even')
        ldB(1, 1, bB);
        if (i < 7) stageA(0, 1, e);
        BAR(); WAIT_LGKM0();
        __builtin_amdgcn_s_setprio(1); mma(0, 1, bB); __builtin_amdgcn_s_setprio(0);
        BAR();
        // ph7: (m1,n1); prefetch B0(odd')  [buf1.B free after ph6]
        ldA(1, 1);
        if (i < 7) stageB(1, 0, e + 1);
        BAR(); WAIT_LGKM0();
        __builtin_amdgcn_s_setprio(1); mma(1, 1, bB); __builtin_amdgcn_s_setprio(0);
        BAR();
        // ph8: (m1,n0); prefetch B1(odd'); vm-wait for even tile
        if (i < 7) stageB(1, 1, e + 1);
        BAR();
        __builtin_amdgcn_s_setprio(1); mma(1, 0, bA); __builtin_amdgcn_s_setprio(0);
        if (i < 7) WAIT_VM4();
        BAR();
    }

    // ---- epilogue ----
    const int h = nt * 4 + wc;                 // wave wc owns one head
    const int b = m0 >> 10;                    // 256-row tile never crosses batch
    const int lbase = (m0 & 1023) + wr * 128;

    float bb[4];
    #pragma unroll
    for (int cn = 0; cn < 4; ++cn)
        bb[cn] = bias[h * 64 + (cn >> 1) * 32 + (cn & 1) * 16 + c];

    if (z < 2) {
        u16* dst = (z == 0) ? qws : kws;
        const float scale = (z == 0) ? 0.125f : 1.0f;
        u16* dbase = dst + (size_t)(b * 16 + h) * 1024 * 64;
        #pragma unroll
        for (int mi = 0; mi < 8; ++mi) {
            const int ro = (mi >> 2) * 64 + (mi & 3) * 16;
            const int rowb = lbase + ro + quad * 4;
            #pragma unroll
            for (int rr = 0; rr < 4; ++rr) {
                u16* drow = dbase + (size_t)(rowb + rr) * 64;
                #pragma unroll
                for (int cn = 0; cn < 4; ++cn) {
                    const int hd = (cn >> 1) * 32 + (cn & 1) * 16 + c;
                    drow[hd] = f2bf((acc[mi][cn][rr] + bb[cn]) * scale);
                }
            }
        }
    } else {
        // V: vtws [B,H,64,1024] dim-major; 4 acc regs = 4 consecutive l -> ushort4
        u16* dbase = vtws + (size_t)(b * 16 + h) * 64 * 1024;
        #pragma unroll
        for (int mi = 0; mi < 8; ++mi) {
            const int ro = (mi >> 2) * 64 + (mi & 3) * 16;
            const int l0 = lbase + ro + quad * 4;
            #pragma unroll
            for (int cn = 0; cn < 4; ++cn) {
                const int hd = (cn >> 1) * 32 + (cn & 1) * 16 + c;
                ushort4 pk;
                pk.x = f2bf(acc[mi][cn][0] + bb[cn]);
                pk.y = f2bf(acc[mi][cn][1] + bb[cn]);
                pk.z = f2bf(acc[mi][cn][2] + bb[cn]);
                pk.w = f2bf(acc[mi][cn][3] + bb[cn]);
                *(ushort4*)(dbase + (size_t)hd * 1024 + l0) = pk;
            }
        }
    }
}

// ---------------------------------------------------------------------------
// Output projection v4: 2-phase counted pipeline (unchanged this round)
// ---------------------------------------------------------------------------
__global__ __launch_bounds__(256) void gemm_out(
    const u16* __restrict__ A, const u16* __restrict__ Wot,
    const float* __restrict__ bo, float* __restrict__ out)
{
    __shared__ u16 As[2][128 * 64];   // 32 KB
    __shared__ u16 Bs[2][64 * 64];    // 16 KB
    const int f = blockIdx.x;
    const int xcd = f & 7, k = f >> 3;
    const int m0 = (xcd * 4 + (k & 3)) * 128;
    const int n0 = (k >> 2) * 64;
    const int t = threadIdx.x;
    const int w = t >> 6, lane = t & 63;
    const int quad = lane >> 4, c = lane & 15;
    const int cx = c & 7;

    const int sr = w * 8 + (lane >> 3);
    const int gch = (lane & 7) ^ ((lane >> 3) & 7);
    const u16* gA = A + (size_t)(m0 + sr) * 1024 + gch * 8;
    const u16* gB = Wot + (size_t)(n0 + sr) * 1024 + gch * 8;

    const int arow = (w >> 1) * 64 + c;
    const int brow = (w & 1) * 32 + c;

    auto stage = [&](int par, int kt) {        // 6 glds16 per thread
        #pragma unroll
        for (int i = 0; i < 4; ++i)
            glds16(As[par] + (i * 32 + w * 8) * 64, gA + (size_t)i * 32 * 1024 + kt);
        #pragma unroll
        for (int i = 0; i < 2; ++i)
            glds16(Bs[par] + (i * 32 + w * 8) * 64, gB + (size_t)i * 32 * 1024 + kt);
    };

    f32x4 acc[4][2] = {};
    stage(0, 0);
    stage(1, 64);
    // outstanding: 12. steady state: wait(6) -> tile i landed, tile i+1 in flight.
    #pragma unroll 1
    for (int i = 0; i < 16; ++i) {
        const int cur = i & 1;
        if (i < 15) { WAIT_VM6(); } else { WAIT_VM0(); }
        BAR();
        #pragma unroll
        for (int kh = 0; kh < 2; ++kh) {
            const int ch = (kh * 4 + quad);
            short8 af[4], bf[2];
            #pragma unroll
            for (int rs = 0; rs < 4; ++rs)
                af[rs] = *(const short8*)(As[cur] + (arow + rs * 16) * 64 + (ch ^ cx) * 8);
            #pragma unroll
            for (int cs = 0; cs < 2; ++cs)
                bf[cs] = *(const short8*)(Bs[cur] + (brow + cs * 16) * 64 + (ch ^ cx) * 8);
            #pragma unroll
            for (int rs = 0; rs < 4; ++rs)
                #pragma unroll
                for (int cs = 0; cs < 2; ++cs)
                    acc[rs][cs] = __builtin_amdgcn_mfma_f32_16x16x32_bf16(
                        af[rs], bf[cs], acc[rs][cs], 0, 0, 0);
        }
        BAR();                       // all waves done reading buf cur
        if (i < 14) stage(cur, (i + 2) * 64);
    }

    const int nb = n0 + (w & 1) * 32;
    float bb[2];
    #pragma unroll
    for (int cs = 0; cs < 2; ++cs) bb[cs] = bo[nb + cs * 16 + c];

    #pragma unroll
    for (int rs = 0; rs < 4; ++rs) {
        #pragma unroll
        for (int r = 0; r < 4; ++r) {
            const int row = m0 + (w >> 1) * 64 + rs * 16 + quad * 4 + r;
            float* orow = out + (size_t)row * 1024 + nb;
            #pragma unroll
            for (int cs = 0; cs < 2; ++cs)
                orow[cs * 16 + c] = acc[rs][cs][r] + bb[cs];
        }
    }
}

// ---------------------------------------------------------------------------
// MFMA flash attention v8: 32 q-rows per wave (2 row-blocks) — the measured
// optimum between v6 (16 rows: DS-pipe-bound, ~31us of DS issue/CU) and v7
// (64 rows: 1 blk/CU, 0.75 waves/SIMD, latency-bound, 45us). 32 rows halves
// the K/V-fragment DS traffic vs v6 (20.5 -> 10.2 us/CU) while grid 512 keeps
// 2 blocks/CU = 2 waves/SIMD for latency hiding.
// Pipeline (dbuf + counted vmcnt(4)), swizzles, P layout: carried over intact.
// ---------------------------------------------------------------------------
__global__ __launch_bounds__(256) void attn_mfma(
    const u16* __restrict__ qws, const u16* __restrict__ kws,
    const u16* __restrict__ vtws, u16* __restrict__ multi,
    float* __restrict__ resid)
{
    __shared__ u16 Ks[2][64 * 64];     // [par][key][dim], chunk-swizzled (16 KB)
    __shared__ u16 Vs[2][64 * 64];     // [par][dim][key], chunk-swizzled (16 KB)
    __shared__ u16 Ps[4][16 * 64];     // per-wave P [16][64], chunk-XOR swizzled (8 KB)
    const int t = threadIdx.x;
    const int wave = t >> 6, lane = t & 63;
    const int quad = lane >> 4, c = lane & 15;
    const int cx = c & 7;
    const int f = blockIdx.x;                  // 512 blocks
    const int xcd = f & 7, j = f >> 3;         // j 0..63
    const int bh = xcd * 8 + (j & 7);          // 8 heads per XCD (KV L2-resident)
    const int qt = j >> 3;                     // 0..7
    const int b = bh >> 4, h = bh & 15;
    const int q0 = qt * 128 + wave * 32;       // 32 q-rows per wave

    const u16* qb = qws + ((size_t)bh * 1024 + q0) * 64;
    const u16* kb = kws + (size_t)bh * 65536;
    const u16* vb = vtws + (size_t)bh * 65536;

    // Q fragments for 2 row-blocks (rows rb*16 + c), k-halves 0/1
    short8 qa[2][2];
    #pragma unroll
    for (int rb = 0; rb < 2; ++rb) {
        qa[rb][0] = *(const short8*)(qb + (size_t)(rb * 16 + c) * 64 + quad * 8);
        qa[rb][1] = *(const short8*)(qb + (size_t)(rb * 16 + c) * 64 + 32 + quad * 8);
    }

    const int srow = wave * 16 + (lane >> 3);
    const int gch = (lane & 7) ^ ((lane >> 3) & 7);
    const u16* gK0 = kb + (size_t)srow * 64 + gch * 8;
    const u16* gK1 = kb + (size_t)(srow + 8) * 64 + gch * 8;
    const u16* gV0 = vb + (size_t)srow * 1024 + gch * 8;
    const u16* gV1 = vb + (size_t)(srow + 8) * 1024 + gch * 8;

    // 4 glds16 per stage -> vmcnt +4; steady-state outstanding = 8 (2 tiles)
    auto stage = [&](int par, int kt) {
        glds16(Ks[par] + (wave * 16) * 64,     gK0 + (size_t)kt * 64);
        glds16(Ks[par] + (wave * 16 + 8) * 64, gK1 + (size_t)kt * 64);
        glds16(Vs[par] + (wave * 16) * 64,     gV0 + kt);
        glds16(Vs[par] + (wave * 16 + 8) * 64, gV1 + kt);
    };

    f32x4 O[2][4] = {};                // [rb][nt]
    float ps[2][4] = {};               // [rb][r]
    u16* pw = &Ps[wave][0];

    stage(0, 0);
    stage(1, 64);

    #pragma unroll 1
    for (int i = 0; i < 16; ++i) {
        const int cur = i & 1;
        if (i < 15) { WAIT_VM4(); } else { WAIT_VM0(); }  // tile i landed
        BAR();

        const u16* Kc = Ks[cur];
        const u16* Vc = Vs[cur];

        // hoist K/V fragments once per tile; reused by both row-blocks
        short8 kf[4][2], vf[4][2];
        #pragma unroll
        for (int nt = 0; nt < 4; ++nt) {
            const u16* kr = Kc + (nt * 16 + c) * 64;
            kf[nt][0] = *(const short8*)(kr + ((quad ^ cx)) * 8);
            kf[nt][1] = *(const short8*)(kr + (((4 + quad) ^ cx)) * 8);
            const u16* vr = Vc + (nt * 16 + c) * 64;
            vf[nt][0] = *(const short8*)(vr + ((quad ^ cx)) * 8);
            vf[nt][1] = *(const short8*)(vr + (((4 + quad) ^ cx)) * 8);
        }

        #pragma unroll
        for (int rb = 0; rb < 2; ++rb) {
            f32x4 s[4];
            __builtin_amdgcn_s_setprio(1);
            #pragma unroll
            for (int nt = 0; nt < 4; ++nt) {
                f32x4 z = {};
                z = __builtin_amdgcn_mfma_f32_16x16x32_bf16(qa[rb][0], kf[nt][0], z, 0, 0, 0);
                z = __builtin_amdgcn_mfma_f32_16x16x32_bf16(qa[rb][1], kf[nt][1], z, 0, 0, 0);
                s[nt] = z;
            }
            __builtin_amdgcn_s_setprio(0);

            // P store: row prow = quad*4+r, col = nt*16+c; chunk' = chunk ^ (prow&7)
            #pragma unroll
            for (int nt = 0; nt < 4; ++nt)
                #pragma unroll
                for (int r = 0; r < 4; ++r) {
                    float p = __expf(s[nt][r]);
                    ps[rb][r] += p;
                    const int prow = quad * 4 + r;
                    pw[prow * 64 + (((nt * 2 + (c >> 3)) ^ (prow & 7)) * 8) + (c & 7)]
                        = (u16)(__float_as_uint(p) >> 16);
                }
            short8 pa0 = *(const short8*)(pw + c * 64 + ((quad ^ cx)) * 8);
            short8 pa1 = *(const short8*)(pw + c * 64 + (((4 + quad) ^ cx)) * 8);

            __builtin_amdgcn_s_setprio(1);
            #pragma unroll
            for (int nt = 0; nt < 4; ++nt) {
                O[rb][nt] = __builtin_amdgcn_mfma_f32_16x16x32_bf16(pa0, vf[nt][0], O[rb][nt], 0, 0, 0);
                O[rb][nt] = __builtin_amdgcn_mfma_f32_16x16x32_bf16(pa1, vf[nt][1], O[rb][nt], 0, 0, 0);
            }
            __builtin_amdgcn_s_setprio(0);
        }

        BAR();                         // all waves done reading buf cur
        if (i < 14) stage(cur, (i + 2) * 64);
    }

    #pragma unroll
    for (int rb = 0; rb < 2; ++rb) {
        float inv[4];
        #pragma unroll
        for (int r = 0; r < 4; ++r) {
            float sum = ps[rb][r];
            sum += __shfl_xor(sum, 1);
            sum += __shfl_xor(sum, 2);
            sum += __shfl_xor(sum, 4);
            sum += __shfl_xor(sum, 8);
            inv[r] = 1.0f / sum;
        }
        u16* ob = multi + ((size_t)b * 1024 + q0 + rb * 16 + quad * 4) * 1024 + h * 64 + c;
        #pragma unroll
        for (int r = 0; r < 4; ++r) {
            u16* orow = ob + (size_t)r * 1024;
            orow[0]  = f2bf(O[rb][0][r] * inv[r]);
            orow[16] = f2bf(O[rb][1][r] * inv[r]);
            orow[32] = f2bf(O[rb][2][r] * inv[r]);
            orow[48] = f2bf(O[rb][3][r] * inv[r]);
        }

        // resid epilogue: lane holds Q[q0+rb*16+c][quad*8..] in qa[rb] (scaled 1/8)
        float* rr = resid + ((size_t)b * 1024 + q0 + rb * 16 + c) * 1024 + h * 64;
        #pragma unroll
        for (int jj = 0; jj < 8; ++jj) {
            rr[quad * 8 + jj]      = bf2f((u16)qa[rb][0][jj]) * 8.0f;
            rr[32 + quad * 8 + jj] = bf2f((u16)qa[rb][1][jj]) * 8.0f;
        }
    }
}

extern "C" void kernel_launch(void* const* d_in, const int* in_sizes, int n_in,
                              void* d_out, int out_size, void* d_ws, size_t ws_size,
                              hipStream_t stream) {
    const float* queries = (const float*)d_in[0];
    const float* context = (const float*)d_in[1];
    const float* Wq = (const float*)d_in[2];
    const float* bq = (const float*)d_in[3];
    const float* Wk = (const float*)d_in[4];
    const float* bk = (const float*)d_in[5];
    const float* Wv = (const float*)d_in[6];
    const float* bv = (const float*)d_in[7];
    const float* Wo = (const float*)d_in[8];
    const float* bo = (const float*)d_in[9];

    float* out = (float*)d_out;                     // [4,1024,1024] f32
    float* resid = out + (size_t)4 * 1024 * 1024;   // [4,1024,1024] f32

    const size_t M1 = 1024 * 1024;
    u16* Aq   = (u16*)d_ws;          // 4M
    u16* Ac   = Aq + 4 * M1;         // 4M
    u16* Wqt  = Ac + 4 * M1;         // 1M
    u16* Wkt  = Wqt + M1;            // 1M
    u16* Wvt  = Wkt + M1;            // 1M
    u16* Wot  = Wvt + M1;            // 1M
    u16* qws  = Wot + M1;            // 4M (pre-scaled 0.125)
    u16* kws  = qws + 4 * M1;        // 4M
    u16* vtws = kws + 4 * M1;        // 4M [B,H,64,1024]
    u16* mws  = vtws + 4 * M1;       // 4M [B,1024,1024]

    prep<<<5120, 256, 0, stream>>>(queries, context, Wq, Wk, Wv, Wo,
                                   Aq, Ac, Wqt, Wkt, Wvt, Wot);
    gemm_qkv8<<<192, 512, 0, stream>>>(Aq, Ac, Wqt, Wkt, Wvt,
                                       bq, bk, bv, qws, kws, vtws);
    attn_mfma<<<512, 256, 0, stream>>>(qws, kws, vtws, mws, resid);
    gemm_out<<<512, 256, 0, stream>>>(mws, Wot, bo, out);
}

// Round 5
// 188.412 us; speedup vs baseline: 1.0590x; 1.0126x over previous
//
#include <hip/hip_runtime.h>
#include <hip/hip_bf16.h>

// Shapes: B=4, LQ=LKV=1024, D=1024, H=16, HD=64, N=H*HD=1024, M=B*LQ=4096
// ws (u16, 56 MB): Aq 4M | Ac 4M | Wqt 1M | Wkt 1M | Wvt 1M | Wot 1M |
//                  qws 4M (x0.125) | kws 4M | vtws 4M (dim-major) | mws 4M

typedef unsigned short u16;
typedef __attribute__((ext_vector_type(8))) short short8;   // 8 bf16 = 4 VGPRs
typedef __attribute__((ext_vector_type(4))) float f32x4;

__device__ __forceinline__ float bf2f(u16 u) {
    union { unsigned int i; float f; } c;
    c.i = ((unsigned int)u) << 16;
    return c.f;
}

__device__ __forceinline__ u16 f2bf(float f) {
    unsigned int x = __float_as_uint(f);
    unsigned int r = (x + 0x7fffu + ((x >> 16) & 1u)) >> 16;  // RNE
    return (u16)r;
}

// async global->LDS, 16B/lane; lds base MUST be wave-uniform (HW adds lane*16)
__device__ __forceinline__ void glds16(u16* lds, const u16* g) {
    __builtin_amdgcn_global_load_lds(
        (const __attribute__((address_space(1))) void*)g,
        (__attribute__((address_space(3))) void*)lds, 16, 0, 0);
}

// raw-barrier discipline (no __syncthreads in pipelined loops: it drains vmcnt)
#define FENCE() asm volatile("" ::: "memory")
#define BAR() do { FENCE(); __builtin_amdgcn_s_barrier(); FENCE(); } while (0)
#define WAIT_VM8() do { asm volatile("s_waitcnt vmcnt(8)" ::: "memory"); \
                        __builtin_amdgcn_sched_barrier(0); } while (0)
#define WAIT_VM6() do { asm volatile("s_waitcnt vmcnt(6)" ::: "memory"); \
                        __builtin_amdgcn_sched_barrier(0); } while (0)
#define WAIT_VM4() do { asm volatile("s_waitcnt vmcnt(4)" ::: "memory"); \
                        __builtin_amdgcn_sched_barrier(0); } while (0)
#define WAIT_VM0() do { asm volatile("s_waitcnt vmcnt(0)" ::: "memory"); \
                        __builtin_amdgcn_sched_barrier(0); } while (0)

// ---------------------------------------------------------------------------
// Fused pre-pass, flat grid 5120 blocks x 256 thr (unchanged)
// ---------------------------------------------------------------------------
__global__ __launch_bounds__(256) void prep(
    const float* __restrict__ q, const float* __restrict__ ctx,
    const float* __restrict__ Wq, const float* __restrict__ Wk,
    const float* __restrict__ Wv, const float* __restrict__ Wo,
    u16* __restrict__ Aq, u16* __restrict__ Ac,
    u16* __restrict__ Wqt, u16* __restrict__ Wkt,
    u16* __restrict__ Wvt, u16* __restrict__ Wot)
{
    __shared__ float ls[64][65];
    const int t = threadIdx.x;
    int bid = blockIdx.x;

    if (bid < 4096) {
        const float* in = (bid < 2048) ? q : ctx;
        u16* out = (bid < 2048) ? Aq : Ac;
        size_t i = ((size_t)(bid & 2047) * 256 + t) * 8;
        float4 v0 = *(const float4*)(in + i);
        float4 v1 = *(const float4*)(in + i + 4);
        short8 p;
        p[0] = (short)f2bf(v0.x); p[1] = (short)f2bf(v0.y);
        p[2] = (short)f2bf(v0.z); p[3] = (short)f2bf(v0.w);
        p[4] = (short)f2bf(v1.x); p[5] = (short)f2bf(v1.y);
        p[6] = (short)f2bf(v1.z); p[7] = (short)f2bf(v1.w);
        *(short8*)(out + i) = p;
        return;
    }
    bid -= 4096;
    const float* in; u16* out; int C; size_t moff; int rt, ct;
    if (bid < 768) {
        const int m = bid >> 8, idx = bid & 255;
        in = (m == 0) ? Wq : (m == 1) ? Wk : Wv;
        out = (m == 0) ? Wqt : (m == 1) ? Wkt : Wvt;
        C = 64; rt = (idx & 15) * 64; ct = 0; moff = (size_t)(idx >> 4) * 65536;
    } else {
        const int idx = bid - 768;
        in = Wo; out = Wot; C = 1024; moff = 0;
        rt = (idx & 15) * 64; ct = (idx >> 4) * 64;
    }
    #pragma unroll
    for (int i = 0; i < 4; ++i) {
        int s = i * 256 + t;
        int row = s >> 4, chunk = s & 15;
        float4 v = *(const float4*)(in + moff + (size_t)(rt + row) * C + ct + chunk * 4);
        ls[row][chunk * 4 + 0] = v.x;
        ls[row][chunk * 4 + 1] = v.y;
        ls[row][chunk * 4 + 2] = v.z;
        ls[row][chunk * 4 + 3] = v.w;
    }
    __syncthreads();
    #pragma unroll
    for (int i = 0; i < 2; ++i) {
        int s = i * 256 + t;
        int n = s >> 3, kc = s & 7;
        short8 p;
        #pragma unroll
        for (int j = 0; j < 8; ++j) p[j] = (short)f2bf(ls[kc * 8 + j][n]);
        *(short8*)(out + moff + (size_t)(ct + n) * 1024 + rt + kc * 8) = p;
    }
}

// ---------------------------------------------------------------------------
// Q/K/V projection v5: 256x256 tile, BK=64, SIMPLE 2-phase counted pipeline.
// The 8-phase port wrapped COMPILER ds_reads in 16x lgkmcnt(0)+sched_barrier(0)
// per 2 K-tiles — m141's order-pinning pathology (874->510 TF there). Fix:
// zero manual lgkm/sched barriers; compiler emits fine-grained lgkmcnt and
// software-pipelines ds_reads into the 64-MFMA cluster. Counted vmcnt(8) dbuf
// (stage tile i+2 after compute of tile i; full-tile latency window).
// grid = 192 blocks x 512 thr (8 waves, 2Mx4N; per-wave 128x64 output).
// Swizzle, XCD mapping, epilogue, acc layout: carried over bit-identical.
// ---------------------------------------------------------------------------
__global__ __launch_bounds__(512) void gemm_qkv2(
    const u16* __restrict__ Aq, const u16* __restrict__ Ac,
    const u16* __restrict__ Wqt, const u16* __restrict__ Wkt,
    const u16* __restrict__ Wvt,
    const float* __restrict__ bq, const float* __restrict__ bk,
    const float* __restrict__ bv,
    u16* __restrict__ qws, u16* __restrict__ kws, u16* __restrict__ vtws)
{
    __shared__ u16 lds[2][2][256 * 64];   // [parity][0=A,1=B][row][k]  128 KB

    const int tid = threadIdx.x;
    const int w = tid >> 6, lane = tid & 63;
    const int wr = w >> 2, wc = w & 3;                 // 2 x 4 wave grid
    const int quad = lane >> 4, c = lane & 15, cx = c & 7;
    const int sr = tid >> 3;                           // staging row (0..63)
    const int gch = (tid & 7) ^ (sr & 7);              // source-side swizzle

    // 192 blocks: xcd owns 2 mtiles x 4 nt x 3 z (24 blocks, all co-resident)
    const int f = blockIdx.x;
    const int xcd = f & 7, r = f >> 3;                 // r 0..23
    const int z = r >> 3;                              // 0..2
    const int mt = xcd * 2 + ((r >> 2) & 1);           // 0..15
    const int nt = r & 3;                              // 0..3
    const int m0 = mt * 256, n0 = nt * 256;

    const u16* A = (z == 0) ? Aq : Ac;
    const u16* Wt = (z == 0) ? Wqt : (z == 1) ? Wkt : Wvt;
    const float* bias = (z == 0) ? bq : (z == 1) ? bk : bv;

    const u16* gAt = A + (size_t)(m0 + sr) * 1024 + gch * 8;
    const u16* gBt = Wt + (size_t)(n0 + sr) * 1024 + gch * 8;

    // one full 256-row A tile + 256-row B tile: 8 glds16 per thread
    auto stage = [&](int par, int t) {
        #pragma unroll
        for (int i = 0; i < 4; ++i) {
            glds16(&lds[par][0][(i * 64 + w * 8) * 64],
                   gAt + (size_t)(i * 64) * 1024 + t * 64);
            glds16(&lds[par][1][(i * 64 + w * 8) * 64],
                   gBt + (size_t)(i * 64) * 1024 + t * 64);
        }
    };

    f32x4 acc[8][4] = {};          // [mh*4+mf][nh*2+nf]
    short8 aq[4][2], bA[2][2], bB[2][2];

    auto ldA = [&](int par, int mh) {
        #pragma unroll
        for (int mf = 0; mf < 4; ++mf)
            #pragma unroll
            for (int ks = 0; ks < 2; ++ks)
                aq[mf][ks] = *(const short8*)&lds[par][0][
                    (wr * 128 + mh * 64 + mf * 16 + c) * 64 + (((ks * 4 + quad) ^ cx) * 8)];
    };
    auto ldB = [&](int par, int nh, short8 (&bq_)[2][2]) {
        #pragma unroll
        for (int nf = 0; nf < 2; ++nf)
            #pragma unroll
            for (int ks = 0; ks < 2; ++ks)
                bq_[nf][ks] = *(const short8*)&lds[par][1][
                    (wc * 64 + nh * 32 + nf * 16 + c) * 64 + (((ks * 4 + quad) ^ cx) * 8)];
    };
    auto mma = [&](int mh, int nh, short8 (&bq_)[2][2]) {
        #pragma unroll
        for (int mf = 0; mf < 4; ++mf)
            #pragma unroll
            for (int nf = 0; nf < 2; ++nf)
                #pragma unroll
                for (int ks = 0; ks < 2; ++ks)
                    acc[mh * 4 + mf][nh * 2 + nf] =
                        __builtin_amdgcn_mfma_f32_16x16x32_bf16(
                            aq[mf][ks], bq_[nf][ks], acc[mh * 4 + mf][nh * 2 + nf], 0, 0, 0);
    };

    stage(0, 0);
    stage(1, 1);
    // outstanding: 16. steady state: wait(8) -> tile i landed, tile i+1 in flight.
    #pragma unroll 1
    for (int i = 0; i < 16; ++i) {
        const int cur = i & 1;
        if (i < 15) { WAIT_VM8(); } else { WAIT_VM0(); }
        BAR();
        // quadrant order with fragment reuse; compiler schedules ds_reads freely
        ldA(cur, 0);
        ldB(cur, 0, bA);
        mma(0, 0, bA);
        ldB(cur, 1, bB);
        mma(0, 1, bB);
        ldA(cur, 1);
        mma(1, 1, bB);
        mma(1, 0, bA);
        BAR();                       // all waves done reading buf cur
        if (i < 14) stage(cur, i + 2);
    }

    // ---- epilogue ----
    const int h = nt * 4 + wc;                 // wave wc owns one head
    const int b = m0 >> 10;                    // 256-row tile never crosses batch
    const int lbase = (m0 & 1023) + wr * 128;

    float bb[4];
    #pragma unroll
    for (int cn = 0; cn < 4; ++cn)
        bb[cn] = bias[h * 64 + (cn >> 1) * 32 + (cn & 1) * 16 + c];

    if (z < 2) {
        u16* dst = (z == 0) ? qws : kws;
        const float scale = (z == 0) ? 0.125f : 1.0f;
        u16* dbase = dst + (size_t)(b * 16 + h) * 1024 * 64;
        #pragma unroll
        for (int mi = 0; mi < 8; ++mi) {
            const int ro = (mi >> 2) * 64 + (mi & 3) * 16;
            const int rowb = lbase + ro + quad * 4;
            #pragma unroll
            for (int rr = 0; rr < 4; ++rr) {
                u16* drow = dbase + (size_t)(rowb + rr) * 64;
                #pragma unroll
                for (int cn = 0; cn < 4; ++cn) {
                    const int hd = (cn >> 1) * 32 + (cn & 1) * 16 + c;
                    drow[hd] = f2bf((acc[mi][cn][rr] + bb[cn]) * scale);
                }
            }
        }
    } else {
        // V: vtws [B,H,64,1024] dim-major; 4 acc regs = 4 consecutive l -> ushort4
        u16* dbase = vtws + (size_t)(b * 16 + h) * 64 * 1024;
        #pragma unroll
        for (int mi = 0; mi < 8; ++mi) {
            const int ro = (mi >> 2) * 64 + (mi & 3) * 16;
            const int l0 = lbase + ro + quad * 4;
            #pragma unroll
            for (int cn = 0; cn < 4; ++cn) {
                const int hd = (cn >> 1) * 32 + (cn & 1) * 16 + c;
                ushort4 pk;
                pk.x = f2bf(acc[mi][cn][0] + bb[cn]);
                pk.y = f2bf(acc[mi][cn][1] + bb[cn]);
                pk.z = f2bf(acc[mi][cn][2] + bb[cn]);
                pk.w = f2bf(acc[mi][cn][3] + bb[cn]);
                *(ushort4*)(dbase + (size_t)hd * 1024 + l0) = pk;
            }
        }
    }
}

// ---------------------------------------------------------------------------
// Output projection v4: 2-phase counted pipeline (unchanged this round)
// ---------------------------------------------------------------------------
__global__ __launch_bounds__(256) void gemm_out(
    const u16* __restrict__ A, const u16* __restrict__ Wot,
    const float* __restrict__ bo, float* __restrict__ out)
{
    __shared__ u16 As[2][128 * 64];   // 32 KB
    __shared__ u16 Bs[2][64 * 64];    // 16 KB
    const int f = blockIdx.x;
    const int xcd = f & 7, k = f >> 3;
    const int m0 = (xcd * 4 + (k & 3)) * 128;
    const int n0 = (k >> 2) * 64;
    const int t = threadIdx.x;
    const int w = t >> 6, lane = t & 63;
    const int quad = lane >> 4, c = lane & 15;
    const int cx = c & 7;

    const int sr = w * 8 + (lane >> 3);
    const int gch = (lane & 7) ^ ((lane >> 3) & 7);
    const u16* gA = A + (size_t)(m0 + sr) * 1024 + gch * 8;
    const u16* gB = Wot + (size_t)(n0 + sr) * 1024 + gch * 8;

    const int arow = (w >> 1) * 64 + c;
    const int brow = (w & 1) * 32 + c;

    auto stage = [&](int par, int kt) {        // 6 glds16 per thread
        #pragma unroll
        for (int i = 0; i < 4; ++i)
            glds16(As[par] + (i * 32 + w * 8) * 64, gA + (size_t)i * 32 * 1024 + kt);
        #pragma unroll
        for (int i = 0; i < 2; ++i)
            glds16(Bs[par] + (i * 32 + w * 8) * 64, gB + (size_t)i * 32 * 1024 + kt);
    };

    f32x4 acc[4][2] = {};
    stage(0, 0);
    stage(1, 64);
    // outstanding: 12. steady state: wait(6) -> tile i landed, tile i+1 in flight.
    #pragma unroll 1
    for (int i = 0; i < 16; ++i) {
        const int cur = i & 1;
        if (i < 15) { WAIT_VM6(); } else { WAIT_VM0(); }
        BAR();
        #pragma unroll
        for (int kh = 0; kh < 2; ++kh) {
            const int ch = (kh * 4 + quad);
            short8 af[4], bf[2];
            #pragma unroll
            for (int rs = 0; rs < 4; ++rs)
                af[rs] = *(const short8*)(As[cur] + (arow + rs * 16) * 64 + (ch ^ cx) * 8);
            #pragma unroll
            for (int cs = 0; cs < 2; ++cs)
                bf[cs] = *(const short8*)(Bs[cur] + (brow + cs * 16) * 64 + (ch ^ cx) * 8);
            #pragma unroll
            for (int rs = 0; rs < 4; ++rs)
                #pragma unroll
                for (int cs = 0; cs < 2; ++cs)
                    acc[rs][cs] = __builtin_amdgcn_mfma_f32_16x16x32_bf16(
                        af[rs], bf[cs], acc[rs][cs], 0, 0, 0);
        }
        BAR();                       // all waves done reading buf cur
        if (i < 14) stage(cur, (i + 2) * 64);
    }

    const int nb = n0 + (w & 1) * 32;
    float bb[2];
    #pragma unroll
    for (int cs = 0; cs < 2; ++cs) bb[cs] = bo[nb + cs * 16 + c];

    #pragma unroll
    for (int rs = 0; rs < 4; ++rs) {
        #pragma unroll
        for (int r = 0; r < 4; ++r) {
            const int row = m0 + (w >> 1) * 64 + rs * 16 + quad * 4 + r;
            float* orow = out + (size_t)row * 1024 + nb;
            #pragma unroll
            for (int cs = 0; cs < 2; ++cs)
                orow[cs * 16 + c] = acc[rs][cs][r] + bb[cs];
        }
    }
}

// ---------------------------------------------------------------------------
// MFMA flash attention v8: 32 q-rows per wave, dbuf + counted vmcnt(4)
// (unchanged this round)
// ---------------------------------------------------------------------------
__global__ __launch_bounds__(256) void attn_mfma(
    const u16* __restrict__ qws, const u16* __restrict__ kws,
    const u16* __restrict__ vtws, u16* __restrict__ multi,
    float* __restrict__ resid)
{
    __shared__ u16 Ks[2][64 * 64];     // [par][key][dim], chunk-swizzled (16 KB)
    __shared__ u16 Vs[2][64 * 64];     // [par][dim][key], chunk-swizzled (16 KB)
    __shared__ u16 Ps[4][16 * 64];     // per-wave P [16][64], chunk-XOR swizzled (8 KB)
    const int t = threadIdx.x;
    const int wave = t >> 6, lane = t & 63;
    const int quad = lane >> 4, c = lane & 15;
    const int cx = c & 7;
    const int f = blockIdx.x;                  // 512 blocks
    const int xcd = f & 7, j = f >> 3;         // j 0..63
    const int bh = xcd * 8 + (j & 7);          // 8 heads per XCD (KV L2-resident)
    const int qt = j >> 3;                     // 0..7
    const int b = bh >> 4, h = bh & 15;
    const int q0 = qt * 128 + wave * 32;       // 32 q-rows per wave

    const u16* qb = qws + ((size_t)bh * 1024 + q0) * 64;
    const u16* kb = kws + (size_t)bh * 65536;
    const u16* vb = vtws + (size_t)bh * 65536;

    // Q fragments for 2 row-blocks (rows rb*16 + c), k-halves 0/1
    short8 qa[2][2];
    #pragma unroll
    for (int rb = 0; rb < 2; ++rb) {
        qa[rb][0] = *(const short8*)(qb + (size_t)(rb * 16 + c) * 64 + quad * 8);
        qa[rb][1] = *(const short8*)(qb + (size_t)(rb * 16 + c) * 64 + 32 + quad * 8);
    }

    const int srow = wave * 16 + (lane >> 3);
    const int gch = (lane & 7) ^ ((lane >> 3) & 7);
    const u16* gK0 = kb + (size_t)srow * 64 + gch * 8;
    const u16* gK1 = kb + (size_t)(srow + 8) * 64 + gch * 8;
    const u16* gV0 = vb + (size_t)srow * 1024 + gch * 8;
    const u16* gV1 = vb + (size_t)(srow + 8) * 1024 + gch * 8;

    // 4 glds16 per stage -> vmcnt +4; steady-state outstanding = 8 (2 tiles)
    auto stage = [&](int par, int kt) {
        glds16(Ks[par] + (wave * 16) * 64,     gK0 + (size_t)kt * 64);
        glds16(Ks[par] + (wave * 16 + 8) * 64, gK1 + (size_t)kt * 64);
        glds16(Vs[par] + (wave * 16) * 64,     gV0 + kt);
        glds16(Vs[par] + (wave * 16 + 8) * 64, gV1 + kt);
    };

    f32x4 O[2][4] = {};                // [rb][nt]
    float ps[2][4] = {};               // [rb][r]
    u16* pw = &Ps[wave][0];

    stage(0, 0);
    stage(1, 64);

    #pragma unroll 1
    for (int i = 0; i < 16; ++i) {
        const int cur = i & 1;
        if (i < 15) { WAIT_VM4(); } else { WAIT_VM0(); }  // tile i landed
        BAR();

        const u16* Kc = Ks[cur];
        const u16* Vc = Vs[cur];

        // hoist K/V fragments once per tile; reused by both row-blocks
        short8 kf[4][2], vf[4][2];
        #pragma unroll
        for (int nt = 0; nt < 4; ++nt) {
            const u16* kr = Kc + (nt * 16 + c) * 64;
            kf[nt][0] = *(const short8*)(kr + ((quad ^ cx)) * 8);
            kf[nt][1] = *(const short8*)(kr + (((4 + quad) ^ cx)) * 8);
            const u16* vr = Vc + (nt * 16 + c) * 64;
            vf[nt][0] = *(const short8*)(vr + ((quad ^ cx)) * 8);
            vf[nt][1] = *(const short8*)(vr + (((4 + quad) ^ cx)) * 8);
        }

        #pragma unroll
        for (int rb = 0; rb < 2; ++rb) {
            f32x4 s[4];
            __builtin_amdgcn_s_setprio(1);
            #pragma unroll
            for (int nt = 0; nt < 4; ++nt) {
                f32x4 z = {};
                z = __builtin_amdgcn_mfma_f32_16x16x32_bf16(qa[rb][0], kf[nt][0], z, 0, 0, 0);
                z = __builtin_amdgcn_mfma_f32_16x16x32_bf16(qa[rb][1], kf[nt][1], z, 0, 0, 0);
                s[nt] = z;
            }
            __builtin_amdgcn_s_setprio(0);

            // P store: row prow = quad*4+r, col = nt*16+c; chunk' = chunk ^ (prow&7)
            #pragma unroll
            for (int nt = 0; nt < 4; ++nt)
                #pragma unroll
                for (int r = 0; r < 4; ++r) {
                    float p = __expf(s[nt][r]);
                    ps[rb][r] += p;
                    const int prow = quad * 4 + r;
                    pw[prow * 64 + (((nt * 2 + (c >> 3)) ^ (prow & 7)) * 8) + (c & 7)]
                        = (u16)(__float_as_uint(p) >> 16);
                }
            short8 pa0 = *(const short8*)(pw + c * 64 + ((quad ^ cx)) * 8);
            short8 pa1 = *(const short8*)(pw + c * 64 + (((4 + quad) ^ cx)) * 8);

            __builtin_amdgcn_s_setprio(1);
            #pragma unroll
            for (int nt = 0; nt < 4; ++nt) {
                O[rb][nt] = __builtin_amdgcn_mfma_f32_16x16x32_bf16(pa0, vf[nt][0], O[rb][nt], 0, 0, 0);
                O[rb][nt] = __builtin_amdgcn_mfma_f32_16x16x32_bf16(pa1, vf[nt][1], O[rb][nt], 0, 0, 0);
            }
            __builtin_amdgcn_s_setprio(0);
        }

        BAR();                         // all waves done reading buf cur
        if (i < 14) stage(cur, (i + 2) * 64);
    }

    #pragma unroll
    for (int rb = 0; rb < 2; ++rb) {
        float inv[4];
        #pragma unroll
        for (int r = 0; r < 4; ++r) {
            float sum = ps[rb][r];
            sum += __shfl_xor(sum, 1);
            sum += __shfl_xor(sum, 2);
            sum += __shfl_xor(sum, 4);
            sum += __shfl_xor(sum, 8);
            inv[r] = 1.0f / sum;
        }
        u16* ob = multi + ((size_t)b * 1024 + q0 + rb * 16 + quad * 4) * 1024 + h * 64 + c;
        #pragma unroll
        for (int r = 0; r < 4; ++r) {
            u16* orow = ob + (size_t)r * 1024;
            orow[0]  = f2bf(O[rb][0][r] * inv[r]);
            orow[16] = f2bf(O[rb][1][r] * inv[r]);
            orow[32] = f2bf(O[rb][2][r] * inv[r]);
            orow[48] = f2bf(O[rb][3][r] * inv[r]);
        }

        // resid epilogue: lane holds Q[q0+rb*16+c][quad*8..] in qa[rb] (scaled 1/8)
        float* rr = resid + ((size_t)b * 1024 + q0 + rb * 16 + c) * 1024 + h * 64;
        #pragma unroll
        for (int jj = 0; jj < 8; ++jj) {
            rr[quad * 8 + jj]      = bf2f((u16)qa[rb][0][jj]) * 8.0f;
            rr[32 + quad * 8 + jj] = bf2f((u16)qa[rb][1][jj]) * 8.0f;
        }
    }
}

extern "C" void kernel_launch(void* const* d_in, const int* in_sizes, int n_in,
                              void* d_out, int out_size, void* d_ws, size_t ws_size,
                              hipStream_t stream) {
    const float* queries = (const float*)d_in[0];
    const float* context = (const float*)d_in[1];
    const float* Wq = (const float*)d_in[2];
    const float* bq = (const float*)d_in[3];
    const float* Wk = (const float*)d_in[4];
    const float* bk = (const float*)d_in[5];
    const float* Wv = (const float*)d_in[6];
    const float* bv = (const float*)d_in[7];
    const float* Wo = (const float*)d_in[8];
    const float* bo = (const float*)d_in[9];

    float* out = (float*)d_out;                     // [4,1024,1024] f32
    float* resid = out + (size_t)4 * 1024 * 1024;   // [4,1024,1024] f32

    const size_t M1 = 1024 * 1024;
    u16* Aq   = (u16*)d_ws;          // 4M
    u16* Ac   = Aq + 4 * M1;         // 4M
    u16* Wqt  = Ac + 4 * M1;         // 1M
    u16* Wkt  = Wqt + M1;            // 1M
    u16* Wvt  = Wkt + M1;            // 1M
    u16* Wot  = Wvt + M1;            // 1M
    u16* qws  = Wot + M1;            // 4M (pre-scaled 0.125)
    u16* kws  = qws + 4 * M1;        // 4M
    u16* vtws = kws + 4 * M1;        // 4M [B,H,64,1024]
    u16* mws  = vtws + 4 * M1;       // 4M [B,1024,1024]

    prep<<<5120, 256, 0, stream>>>(queries, context, Wq, Wk, Wv, Wo,
                                   Aq, Ac, Wqt, Wkt, Wvt, Wot);
    gemm_qkv2<<<192, 512, 0, stream>>>(Aq, Ac, Wqt, Wkt, Wvt,
                                       bq, bk, bv, qws, kws, vtws);
    attn_mfma<<<512, 256, 0, stream>>>(qws, kws, vtws, mws, resid);
    gemm_out<<<512, 256, 0, stream>>>(mws, Wot, bo, out);
}